// Round 2
// baseline (459.815 us; speedup 1.0000x reference)
//
#include <hip/hip_runtime.h>
#include <hip/hip_bf16.h>

#define IN_CH 128
#define HID_CH 64
#define OUT_CH 32
#define EPB 2048  // edges per partition block
#define MAXB 512  // max buckets (N <= 131072)

typedef unsigned short ushort_t;
typedef __attribute__((ext_vector_type(8))) short short8;
typedef __attribute__((ext_vector_type(4))) float float4v;
using half8 = __attribute__((ext_vector_type(8))) _Float16;

static __device__ __forceinline__ ushort_t f2bf(float f) {
    unsigned u = __float_as_uint(f);
    unsigned r = (u + 0x7fff + ((u >> 16) & 1)) >> 16;  // RNE
    return (ushort_t)r;
}
static __device__ __forceinline__ float bf_lo(unsigned u) { return __uint_as_float(u << 16); }
static __device__ __forceinline__ float bf_hi(unsigned u) { return __uint_as_float(u & 0xffff0000u); }

static __device__ __forceinline__ unsigned f2h2(float lo, float hi) {  // RNE f32->f16 pair, packed
    union { _Float16 h[2]; unsigned u; } v;
    v.h[0] = (_Float16)lo;
    v.h[1] = (_Float16)hi;
    return v.u;
}
static __device__ __forceinline__ unsigned pkh(float a, float b) {  // RTZ packed cvt (fast path)
    auto p = __builtin_amdgcn_cvt_pkrtz(a, b);
    union { decltype(p) h; unsigned u; } v;
    v.h = p;
    return v.u;
}

// ---------------- radix partition by dst>>8 (+ prepW in 5 trailing blocks) ----------------

__global__ __launch_bounds__(256) void k_partition(const int* __restrict__ src,
                                                   const int* __restrict__ dst,
                                                   int* __restrict__ gcursor,
                                                   unsigned* __restrict__ pairs,
                                                   int E, int nbk, int cap, int PB,
                                                   const float* __restrict__ W1,
                                                   const float* __restrict__ W2,
                                                   unsigned* __restrict__ wsW) {
    __shared__ int lhist[MAXB];
    __shared__ int lbase[MAXB];
    __shared__ int lcur[MAXB];
    const int tid = threadIdx.x;

    if (blockIdx.x >= PB) {  // prepW blocks
        int s = (blockIdx.x - PB) * 256 + tid;  // 0..1279
        if (s < 1024) {                          // W1 -> bf16 b-frags
            int lane = s & 63;
            int nt = (s >> 6) & 3;
            int kc = s >> 8;
            int c = nt * 16 + (lane & 15);
            int k0 = kc * 32 + (lane >> 4) * 8;
            unsigned o[4];
#pragma unroll
            for (int d = 0; d < 4; ++d) {
                unsigned lo = f2bf(W1[(k0 + 2 * d) * 64 + c]);
                unsigned hi = f2bf(W1[(k0 + 2 * d + 1) * 64 + c]);
                o[d] = lo | (hi << 16);
            }
            ((uint4*)wsW)[s] = make_uint4(o[0], o[1], o[2], o[3]);
        } else {  // W2 -> f16 b-frags: frag f = kt*2+ct
            int q = s - 1024;  // 0..255
            int lane = q & 63;
            int f = q >> 6;
            int c = (f & 1) * 16 + (lane & 15);
            int k0 = (f >> 1) * 32 + (lane >> 4) * 8;
            unsigned o[4];
#pragma unroll
            for (int d = 0; d < 4; ++d)
                o[d] = f2h2(W2[(k0 + 2 * d) * 32 + c], W2[(k0 + 2 * d + 1) * 32 + c]);
            ((uint4*)wsW)[1024 + q] = make_uint4(o[0], o[1], o[2], o[3]);
        }
        return;
    }

    for (int b = tid; b < nbk; b += 256) { lhist[b] = 0; lcur[b] = 0; }
    __syncthreads();
    int s[8], d[8];
    const int e0 = blockIdx.x * EPB;
#pragma unroll
    for (int j = 0; j < 8; ++j) {
        int e = e0 + j * 256 + tid;
        if (e < E) {
            s[j] = src[e];
            d[j] = dst[e];
            atomicAdd(&lhist[d[j] >> 8], 1);
        } else {
            d[j] = -1;
        }
    }
    __syncthreads();
    for (int b = tid; b < nbk; b += 256)
        lbase[b] = lhist[b] ? atomicAdd(&gcursor[b], lhist[b]) : 0;
    __syncthreads();
#pragma unroll
    for (int j = 0; j < 8; ++j) {
        if (d[j] >= 0) {
            int b = d[j] >> 8;
            int loc = atomicAdd(&lcur[b], 1);
            int idx = lbase[b] + loc;
            if (idx < cap)
                pairs[(long long)b * cap + idx] = ((unsigned)s[j] << 8) | (unsigned)(d[j] & 255);
        }
    }
}

// ---------------- fused per-bucket build (inline bucket-total scan) ----------------

__global__ __launch_bounds__(256) void k_bucket_build(const unsigned* __restrict__ pairs,
                                                      const int* __restrict__ gcursor,
                                                      int* __restrict__ rowptr,
                                                      int* __restrict__ col,
                                                      float* __restrict__ dis,
                                                      unsigned* __restrict__ h1zero,
                                                      int cap, int N) {
    __shared__ int lc[256];
    __shared__ int ls[256];
    __shared__ int lcur[256];
    const int b = blockIdx.x, tid = threadIdx.x;

    if (b == 0 && tid < 32) h1zero[tid] = 0;  // h1 pad row (64 bf16 = 32 dwords)

    int ga = min(gcursor[2 * tid], cap);
    int gb = min(gcursor[2 * tid + 1], cap);
    ls[tid] = ga + gb;
    __syncthreads();
    for (int off = 1; off < 256; off <<= 1) {
        int val = (tid >= off) ? ls[tid - off] : 0;
        __syncthreads();
        ls[tid] += val;
        __syncthreads();
    }
    const int p = b >> 1;
    const int base = (p ? ls[p - 1] : 0) + ((b & 1) ? min(gcursor[b - 1], cap) : 0);
    const int total = ls[255];
    __syncthreads();
    if (b == 0 && tid == 0) rowptr[N] = total;

    lc[tid] = 0;
    __syncthreads();
    const int cnt = min(gcursor[b], cap);
    const unsigned* pp = pairs + (long long)b * cap;
    for (int i = tid; i < cnt; i += 256) atomicAdd(&lc[pp[i] & 255], 1);
    __syncthreads();
    const int v = lc[tid];
    ls[tid] = v;
    __syncthreads();
    for (int off = 1; off < 256; off <<= 1) {
        int val = (tid >= off) ? ls[tid - off] : 0;
        __syncthreads();
        ls[tid] += val;
        __syncthreads();
    }
    const int excl = ls[tid] - v;
    const int row = b * 256 + tid;
    if (row < N) {
        rowptr[row] = base + excl;
        dis[row] = rsqrtf((float)(v + 1));  // +1 self-loop
    }
    lcur[tid] = base + excl;
    __syncthreads();
    for (int i = tid; i < cnt; i += 256) {
        unsigned pk = pp[i];
        int pos = atomicAdd(&lcur[pk & 255], 1);
        col[pos] = (int)(pk >> 8);
    }
}

// ---------------- L1 matmul via MFMA; output pre-scaled: h1' = dis[row]*(x@W1) ----------------
// Also zeroes h2 pad row and initializes the work-dispenser counters.

__global__ __launch_bounds__(256) void k_mm1(const float* __restrict__ X,
                                             const unsigned* __restrict__ wsW,
                                             const float* __restrict__ dis,
                                             ushort_t* __restrict__ H,
                                             unsigned* __restrict__ h2zero,
                                             int* __restrict__ wctr, int initv, int N) {
    const int tid = threadIdx.x;
    if (blockIdx.x == 0 && tid < 16) h2zero[tid] = 0;  // h2 pad row (32 bf16 = 16 dwords)
    if (blockIdx.x == 0 && tid == 0) { wctr[0] = initv; wctr[1] = initv; }

    const int wv = tid >> 6, lane = tid & 63;
    const int quad = lane >> 4, n16 = lane & 15;
    const int rowbase = blockIdx.x * 64 + wv * 16;
    const int myrow = rowbase + n16;
    const bool rok = (myrow < N);

    float4v acc0 = {}, acc1 = {}, acc2 = {}, acc3 = {};

#pragma unroll
    for (int kc = 0; kc < 4; ++kc) {
        float4 xa = make_float4(0.f, 0.f, 0.f, 0.f), xb = xa;
        if (rok) {
            const float4* p = (const float4*)(X + (long long)myrow * 128 + kc * 32 + quad * 8);
            xa = p[0];
            xb = p[1];
        }
        unsigned pk[4];
        pk[0] = (unsigned)f2bf(xa.x) | ((unsigned)f2bf(xa.y) << 16);
        pk[1] = (unsigned)f2bf(xa.z) | ((unsigned)f2bf(xa.w) << 16);
        pk[2] = (unsigned)f2bf(xb.x) | ((unsigned)f2bf(xb.y) << 16);
        pk[3] = (unsigned)f2bf(xb.z) | ((unsigned)f2bf(xb.w) << 16);
        short8 a;
        a[0] = (short)(pk[0] & 0xffff); a[1] = (short)(pk[0] >> 16);
        a[2] = (short)(pk[1] & 0xffff); a[3] = (short)(pk[1] >> 16);
        a[4] = (short)(pk[2] & 0xffff); a[5] = (short)(pk[2] >> 16);
        a[6] = (short)(pk[3] & 0xffff); a[7] = (short)(pk[3] >> 16);

        const short8* wb = (const short8*)wsW;
        short8 b0 = wb[(kc * 4 + 0) * 64 + lane];
        short8 b1 = wb[(kc * 4 + 1) * 64 + lane];
        short8 b2 = wb[(kc * 4 + 2) * 64 + lane];
        short8 b3 = wb[(kc * 4 + 3) * 64 + lane];

        acc0 = __builtin_amdgcn_mfma_f32_16x16x32_bf16(a, b0, acc0, 0, 0, 0);
        acc1 = __builtin_amdgcn_mfma_f32_16x16x32_bf16(a, b1, acc1, 0, 0, 0);
        acc2 = __builtin_amdgcn_mfma_f32_16x16x32_bf16(a, b2, acc2, 0, 0, 0);
        acc3 = __builtin_amdgcn_mfma_f32_16x16x32_bf16(a, b3, acc3, 0, 0, 0);
    }

#pragma unroll
    for (int i = 0; i < 4; ++i) {
        int row = rowbase + quad * 4 + i;
        if (row < N) {
            float dr = dis[row];
            long long o = (long long)row * 64 + n16;
            H[o]      = f2bf(dr * acc0[i]);
            H[o + 16] = f2bf(dr * acc1[i]);
            H[o + 32] = f2bf(dr * acc2[i]);
            H[o + 48] = f2bf(dr * acc3[i]);
        }
    }
}

// ---------------- fused agg64 + mm2 v2: 8 rows/wave, 8-lane row-groups, no reduce ----------------
// lane (t=lane&7, g=lane>>3): row r0+g, h1 channels 8t..8t+7 (one uint4 = 16B slice).
// Tiers 1-3 (slots 0..23) unconditional with pad->zero-row; tier 4 gated; serial tail >32.
// z rows -> LDS -> one batched 4-MFMA group per 8 rows. Dynamic block dispenser.

__global__ __launch_bounds__(256, 4) void k_agg64_mm2(const unsigned* __restrict__ h,
                                                      const int* __restrict__ rowptr,
                                                      const int* __restrict__ col,
                                                      const float* __restrict__ dis,
                                                      const float* __restrict__ b1,
                                                      const unsigned* __restrict__ wsW2,
                                                      unsigned* __restrict__ h2,
                                                      int* __restrict__ wctr, int N) {
    __shared__ __align__(16) _Float16 zbl[4][8][64];
    const int tid = threadIdx.x;
    const int wv = tid >> 6, lane = tid & 63;
    const int t = lane & 7, g = lane >> 3;
    const float4 bqa = ((const float4*)b1)[2 * t];      // channels 8t..8t+3
    const float4 bqb = ((const float4*)b1)[2 * t + 1];  // channels 8t+4..8t+7

    const half8* wfh = (const half8*)wsW2;  // W2 f16 b-frags (verified layout)
    const half8 bf00 = wfh[lane];
    const half8 bf01 = wfh[64 + lane];
    const half8 bf10 = wfh[128 + lane];
    const half8 bf11 = wfh[192 + lane];

    ushort_t* H2u = (ushort_t*)h2;
    const uint4* h4 = (const uint4*)h;
    const int NB = (N + 7) >> 3;
    int rb = blockIdx.x * 4 + wv;  // first block static; rest via dispenser

    while (rb < NB) {
        const int r0 = rb * 8;
        int rp_l = rowptr[min(r0 + min(lane, 8), N)];
        float dis_l = (lane < 8 && r0 + lane < N) ? dis[r0 + lane] : 0.f;
        const int sg = __shfl(rp_l, g);
        const int dg = __shfl(rp_l, g + 1) - sg;
        const float drg = __shfl(dis_l, g);
        float dr03[4];  // dis of rows (lane>>4&1)*4 + i, for the C-store
#pragma unroll
        for (int i = 0; i < 4; ++i) dr03[i] = __shfl(dis_l, ((lane >> 4) & 1) * 4 + i);

        int mc1 = N, mc2 = N, mc3 = N;
        if (t < dg)      mc1 = col[sg + t];
        if (8 + t < dg)  mc2 = col[sg + 8 + t];
        if (16 + t < dg) mc3 = col[sg + 16 + t];

        const int rme = min(r0 + g, N);
        uint4 us = h4[rme * 8 + t];  // self-loop slice
        float2 p0 = make_float2(bf_lo(us.x), bf_hi(us.x));
        float2 p1 = make_float2(bf_lo(us.y), bf_hi(us.y));
        float2 p2 = make_float2(bf_lo(us.z), bf_hi(us.z));
        float2 p3 = make_float2(bf_lo(us.w), bf_hi(us.w));

#define GATX(MC, U)                                                   \
    {                                                                 \
        int s_ = __shfl((MC), (g << 3) + (U));                        \
        uint4 uu = h4[s_ * 8 + t];                                    \
        p0 += make_float2(bf_lo(uu.x), bf_hi(uu.x));                  \
        p1 += make_float2(bf_lo(uu.y), bf_hi(uu.y));                  \
        p2 += make_float2(bf_lo(uu.z), bf_hi(uu.z));                  \
        p3 += make_float2(bf_lo(uu.w), bf_hi(uu.w));                  \
    }
#pragma unroll
        for (int u = 0; u < 8; ++u) GATX(mc1, u)
#pragma unroll
        for (int u = 0; u < 8; ++u) GATX(mc2, u)
#pragma unroll
        for (int u = 0; u < 8; ++u) GATX(mc3, u)
        if (__any(dg > 24)) {
            int mc4 = N;
            if (24 + t < dg) mc4 = col[sg + 24 + t];
#pragma unroll
            for (int u = 0; u < 8; ++u) GATX(mc4, u)
        }
        for (int u = 32; u < dg; ++u) {  // ultra-rare serial tail (same-addr broadcast col)
            int s_ = col[sg + u];
            uint4 uu = h4[s_ * 8 + t];
            p0 += make_float2(bf_lo(uu.x), bf_hi(uu.x));
            p1 += make_float2(bf_lo(uu.y), bf_hi(uu.y));
            p2 += make_float2(bf_lo(uu.z), bf_hi(uu.z));
            p3 += make_float2(bf_lo(uu.w), bf_hi(uu.w));
        }
#undef GATX

        // z = relu(b1 + dr*acc) -> f16, lane writes its own 16B slice; no cross-lane reduce
        {
            float z0 = fmaxf(fmaf(drg, p0.x, bqa.x), 0.f);
            float z1 = fmaxf(fmaf(drg, p0.y, bqa.y), 0.f);
            float z2 = fmaxf(fmaf(drg, p1.x, bqa.z), 0.f);
            float z3 = fmaxf(fmaf(drg, p1.y, bqa.w), 0.f);
            float z4 = fmaxf(fmaf(drg, p2.x, bqb.x), 0.f);
            float z5 = fmaxf(fmaf(drg, p2.y, bqb.y), 0.f);
            float z6 = fmaxf(fmaf(drg, p3.x, bqb.z), 0.f);
            float z7 = fmaxf(fmaf(drg, p3.y, bqb.w), 0.f);
            *(uint4*)&zbl[wv][g][8 * t] =
                make_uint4(pkh(z0, z1), pkh(z2, z3), pkh(z4, z5), pkh(z6, z7));
        }
        __builtin_amdgcn_wave_barrier();

        // batched MFMA: A row = lane&15 (rows 8-15 replicate rows 0-7, C rows 8-15 unused)
        const int zr = lane & 7;
        const int ko = (lane >> 4) * 8;
        half8 af0 = *(const half8*)&zbl[wv][zr][ko];
        half8 af1 = *(const half8*)&zbl[wv][zr][ko + 32];
        float4v c0 = {}, c1 = {};
        c0 = __builtin_amdgcn_mfma_f32_16x16x32_f16(af0, bf00, c0, 0, 0, 0);
        c0 = __builtin_amdgcn_mfma_f32_16x16x32_f16(af1, bf10, c0, 0, 0, 0);
        c1 = __builtin_amdgcn_mfma_f32_16x16x32_f16(af0, bf01, c1, 0, 0, 0);
        c1 = __builtin_amdgcn_mfma_f32_16x16x32_f16(af1, bf11, c1, 0, 0, 0);
        __builtin_amdgcn_wave_barrier();

        // C rows 0-7 live in lanes 0-31 (row = (lane>>4)*4 + reg), col = lane&15
        if (lane < 32) {
            const int li = lane >> 4;
            const int cc = lane & 15;
#pragma unroll
            for (int i = 0; i < 4; ++i) {
                int rr = r0 + li * 4 + i;
                if (rr < N) {
                    H2u[rr * 32 + cc]      = f2bf(dr03[i] * c0[i]);
                    H2u[rr * 32 + 16 + cc] = f2bf(dr03[i] * c1[i]);
                }
            }
        }

        int nb = 0;
        if (lane == 0) nb = atomicAdd(wctr, 1);
        rb = __shfl(nb, 0);
    }
}

// ---------------- agg32 v2: 8 rows/wave, 8-lane row-groups, no reduce, fp32 out ----------------

__global__ __launch_bounds__(256, 4) void k_agg32(const unsigned* __restrict__ h,
                                                  const int* __restrict__ rowptr,
                                                  const int* __restrict__ col,
                                                  const float* __restrict__ dis,
                                                  const float* __restrict__ b,
                                                  float* __restrict__ out,
                                                  int* __restrict__ wctr, int N) {
    const int tid = threadIdx.x;
    const int wv = tid >> 6, lane = tid & 63;
    const int t = lane & 7, g = lane >> 3;
    const float4 bq = ((const float4*)b)[t];  // channels 4t..4t+3
    const uint2* hw = (const uint2*)h;
    const int NB = (N + 7) >> 3;
    int rb = blockIdx.x * 4 + wv;

    while (rb < NB) {
        const int r0 = rb * 8;
        int rp_l = rowptr[min(r0 + min(lane, 8), N)];
        float dis_l = (lane < 8 && r0 + lane < N) ? dis[r0 + lane] : 0.f;
        const int sg = __shfl(rp_l, g);
        const int dg = __shfl(rp_l, g + 1) - sg;
        const float drg = __shfl(dis_l, g);

        int mc1 = N, mc2 = N, mc3 = N;
        if (t < dg)      mc1 = col[sg + t];
        if (8 + t < dg)  mc2 = col[sg + 8 + t];
        if (16 + t < dg) mc3 = col[sg + 16 + t];

        const int rme = min(r0 + g, N);
        uint2 us = hw[rme * 8 + t];  // self-loop slice
        float2 p0 = make_float2(bf_lo(us.x), bf_hi(us.x));
        float2 p1 = make_float2(bf_lo(us.y), bf_hi(us.y));

#define GAT2(MC, U)                                                   \
    {                                                                 \
        int s_ = __shfl((MC), (g << 3) + (U));                        \
        uint2 uu = hw[s_ * 8 + t];                                    \
        p0 += make_float2(bf_lo(uu.x), bf_hi(uu.x));                  \
        p1 += make_float2(bf_lo(uu.y), bf_hi(uu.y));                  \
    }
#pragma unroll
        for (int u = 0; u < 8; ++u) GAT2(mc1, u)
#pragma unroll
        for (int u = 0; u < 8; ++u) GAT2(mc2, u)
#pragma unroll
        for (int u = 0; u < 8; ++u) GAT2(mc3, u)
        if (__any(dg > 24)) {
            int mc4 = N;
            if (24 + t < dg) mc4 = col[sg + 24 + t];
#pragma unroll
            for (int u = 0; u < 8; ++u) GAT2(mc4, u)
        }
        for (int u = 32; u < dg; ++u) {
            int s_ = col[sg + u];
            uint2 uu = hw[s_ * 8 + t];
            p0 += make_float2(bf_lo(uu.x), bf_hi(uu.x));
            p1 += make_float2(bf_lo(uu.y), bf_hi(uu.y));
        }
#undef GAT2

        const int rr = r0 + g;
        if (rr < N) {
            float4 o;
            o.x = bq.x + drg * p0.x;
            o.y = bq.y + drg * p0.y;
            o.z = bq.z + drg * p1.x;
            o.w = bq.w + drg * p1.y;
            ((float4*)out)[(long long)rr * 8 + t] = o;
        }

        int nb = 0;
        if (lane == 0) nb = atomicAdd(wctr + 1, 1);
        rb = __shfl(nb, 0);
    }
}

extern "C" void kernel_launch(void* const* d_in, const int* in_sizes, int n_in,
                              void* d_out, int out_size, void* d_ws, size_t ws_size,
                              hipStream_t stream) {
    const float* x  = (const float*)d_in[0];
    const int*   ei = (const int*)d_in[1];
    const float* W1 = (const float*)d_in[2];
    const float* b1 = (const float*)d_in[3];
    const float* W2 = (const float*)d_in[4];
    const float* b2 = (const float*)d_in[5];
    float* out = (float*)d_out;

    const int N = in_sizes[0] / IN_CH;
    const int E = in_sizes[1] / 2;
    const int* esrc = ei;
    const int* edst = ei + E;

    int nbk = (N + 255) >> 8;
    if (nbk > MAXB) nbk = MAXB;
    const int per_b = (E + nbk - 1) / nbk;
    const int cap = per_b + per_b / 4 + 256;  // ~20-sigma headroom

    // workspace layout (4-byte units, regions padded to 16); h1/h2 have pad row N
    int* rowptr   = (int*)d_ws;                          // N+1
    int* gcursor  = rowptr + (((N + 1) + 15) & ~15);     // MAXB
    int* wctr     = gcursor + MAXB;                      // 16 (2 used: agg64, agg32)
    unsigned* wsW = (unsigned*)(wctr + 16);              // 4096 W1-frag + 1024 W2-frag dwords
    int* col      = (int*)(wsW + 5120);                  // E
    float* dis    = (float*)(col + ((E + 15) & ~15));    // N
    ushort_t* h1  = (ushort_t*)(dis + ((N + 15) & ~15)); // (N+1)*64 bf16
    unsigned* scratch = (unsigned*)(h1 + (((long long)(N + 1) * 64 + 31) & ~31LL));
    unsigned* pairs = scratch;        // nbk*cap dwords (~8.4MB), dead after bucket_build
    unsigned* h2    = scratch;        // (N+1)*16 dwords bf16x2, written after pairs dead

    const int B = 256;
    const int PB = (E + EPB - 1) / EPB;
    const int AGG_BLOCKS = 1024;  // persistent; NB=12500 blocks over 4096 waves, dispenser-balanced

    hipMemsetAsync(gcursor, 0, MAXB * sizeof(int), stream);
    k_partition<<<PB + 5, B, 0, stream>>>(esrc, edst, gcursor, pairs, E, nbk, cap, PB, W1, W2, wsW);
    k_bucket_build<<<nbk, B, 0, stream>>>(pairs, gcursor, rowptr, col, dis,
                                          (unsigned*)(h1 + (long long)N * 64), cap, N);

    k_mm1<<<(N + 63) / 64, B, 0, stream>>>(x, wsW, dis, h1, h2 + (long long)N * 16,
                                           wctr, AGG_BLOCKS * 4, N);

    k_agg64_mm2<<<AGG_BLOCKS, B, 0, stream>>>((const unsigned*)h1, rowptr, col, dis, b1,
                                              wsW + 4096, h2, wctr, N);

    k_agg32<<<AGG_BLOCKS, B, 0, stream>>>((const unsigned*)h2, rowptr, col, dis, b2, out,
                                          wctr, N);
}

// Round 3
// 234.699 us; speedup vs baseline: 1.9592x; 1.9592x over previous
//
#include <hip/hip_runtime.h>
#include <hip/hip_bf16.h>

#define IN_CH 128
#define HID_CH 64
#define OUT_CH 32
#define EPB 2048  // edges per partition block
#define MAXB 512  // max buckets (N <= 131072)

typedef unsigned short ushort_t;
typedef __attribute__((ext_vector_type(8))) short short8;
typedef __attribute__((ext_vector_type(4))) float float4v;
using half8 = __attribute__((ext_vector_type(8))) _Float16;

static __device__ __forceinline__ ushort_t f2bf(float f) {
    unsigned u = __float_as_uint(f);
    unsigned r = (u + 0x7fff + ((u >> 16) & 1)) >> 16;  // RNE
    return (ushort_t)r;
}
static __device__ __forceinline__ float bf_lo(unsigned u) { return __uint_as_float(u << 16); }
static __device__ __forceinline__ float bf_hi(unsigned u) { return __uint_as_float(u & 0xffff0000u); }

static __device__ __forceinline__ unsigned f2h2(float lo, float hi) {  // RNE f32->f16 pair, packed
    union { _Float16 h[2]; unsigned u; } v;
    v.h[0] = (_Float16)lo;
    v.h[1] = (_Float16)hi;
    return v.u;
}
static __device__ __forceinline__ unsigned pkh(float a, float b) {  // RTZ packed cvt (fast path)
    auto p = __builtin_amdgcn_cvt_pkrtz(a, b);
    union { decltype(p) h; unsigned u; } v;
    v.h = p;
    return v.u;
}

// ---------------- radix partition by dst>>8 (+ prepW in 5 trailing blocks) ----------------

__global__ __launch_bounds__(256) void k_partition(const int* __restrict__ src,
                                                   const int* __restrict__ dst,
                                                   int* __restrict__ gcursor,
                                                   unsigned* __restrict__ pairs,
                                                   int E, int nbk, int cap, int PB,
                                                   const float* __restrict__ W1,
                                                   const float* __restrict__ W2,
                                                   unsigned* __restrict__ wsW) {
    __shared__ int lhist[MAXB];
    __shared__ int lbase[MAXB];
    __shared__ int lcur[MAXB];
    const int tid = threadIdx.x;

    if (blockIdx.x >= PB) {  // prepW blocks
        int s = (blockIdx.x - PB) * 256 + tid;  // 0..1279
        if (s < 1024) {                          // W1 -> bf16 b-frags
            int lane = s & 63;
            int nt = (s >> 6) & 3;
            int kc = s >> 8;
            int c = nt * 16 + (lane & 15);
            int k0 = kc * 32 + (lane >> 4) * 8;
            unsigned o[4];
#pragma unroll
            for (int d = 0; d < 4; ++d) {
                unsigned lo = f2bf(W1[(k0 + 2 * d) * 64 + c]);
                unsigned hi = f2bf(W1[(k0 + 2 * d + 1) * 64 + c]);
                o[d] = lo | (hi << 16);
            }
            ((uint4*)wsW)[s] = make_uint4(o[0], o[1], o[2], o[3]);
        } else {  // W2 -> f16 b-frags: frag f = kt*2+ct
            int q = s - 1024;  // 0..255
            int lane = q & 63;
            int f = q >> 6;
            int c = (f & 1) * 16 + (lane & 15);
            int k0 = (f >> 1) * 32 + (lane >> 4) * 8;
            unsigned o[4];
#pragma unroll
            for (int d = 0; d < 4; ++d)
                o[d] = f2h2(W2[(k0 + 2 * d) * 32 + c], W2[(k0 + 2 * d + 1) * 32 + c]);
            ((uint4*)wsW)[1024 + q] = make_uint4(o[0], o[1], o[2], o[3]);
        }
        return;
    }

    for (int b = tid; b < nbk; b += 256) { lhist[b] = 0; lcur[b] = 0; }
    __syncthreads();
    int s[8], d[8];
    const int e0 = blockIdx.x * EPB;
#pragma unroll
    for (int j = 0; j < 8; ++j) {
        int e = e0 + j * 256 + tid;
        if (e < E) {
            s[j] = src[e];
            d[j] = dst[e];
            atomicAdd(&lhist[d[j] >> 8], 1);
        } else {
            d[j] = -1;
        }
    }
    __syncthreads();
    for (int b = tid; b < nbk; b += 256)
        lbase[b] = lhist[b] ? atomicAdd(&gcursor[b], lhist[b]) : 0;
    __syncthreads();
#pragma unroll
    for (int j = 0; j < 8; ++j) {
        if (d[j] >= 0) {
            int b = d[j] >> 8;
            int loc = atomicAdd(&lcur[b], 1);
            int idx = lbase[b] + loc;
            if (idx < cap)
                pairs[(long long)b * cap + idx] = ((unsigned)s[j] << 8) | (unsigned)(d[j] & 255);
        }
    }
}

// ---------------- fused per-bucket build (inline bucket-total scan) ----------------

__global__ __launch_bounds__(256) void k_bucket_build(const unsigned* __restrict__ pairs,
                                                      const int* __restrict__ gcursor,
                                                      int* __restrict__ rowptr,
                                                      int* __restrict__ col,
                                                      float* __restrict__ dis,
                                                      unsigned* __restrict__ h1zero,
                                                      int cap, int N) {
    __shared__ int lc[256];
    __shared__ int ls[256];
    __shared__ int lcur[256];
    const int b = blockIdx.x, tid = threadIdx.x;

    if (b == 0 && tid < 32) h1zero[tid] = 0;  // h1 pad row (64 bf16 = 32 dwords)

    int ga = min(gcursor[2 * tid], cap);
    int gb = min(gcursor[2 * tid + 1], cap);
    ls[tid] = ga + gb;
    __syncthreads();
    for (int off = 1; off < 256; off <<= 1) {
        int val = (tid >= off) ? ls[tid - off] : 0;
        __syncthreads();
        ls[tid] += val;
        __syncthreads();
    }
    const int p = b >> 1;
    const int base = (p ? ls[p - 1] : 0) + ((b & 1) ? min(gcursor[b - 1], cap) : 0);
    const int total = ls[255];
    __syncthreads();
    if (b == 0 && tid == 0) rowptr[N] = total;

    lc[tid] = 0;
    __syncthreads();
    const int cnt = min(gcursor[b], cap);
    const unsigned* pp = pairs + (long long)b * cap;
    for (int i = tid; i < cnt; i += 256) atomicAdd(&lc[pp[i] & 255], 1);
    __syncthreads();
    const int v = lc[tid];
    ls[tid] = v;
    __syncthreads();
    for (int off = 1; off < 256; off <<= 1) {
        int val = (tid >= off) ? ls[tid - off] : 0;
        __syncthreads();
        ls[tid] += val;
        __syncthreads();
    }
    const int excl = ls[tid] - v;
    const int row = b * 256 + tid;
    if (row < N) {
        rowptr[row] = base + excl;
        dis[row] = rsqrtf((float)(v + 1));  // +1 self-loop
    }
    lcur[tid] = base + excl;
    __syncthreads();
    for (int i = tid; i < cnt; i += 256) {
        unsigned pk = pp[i];
        int pos = atomicAdd(&lcur[pk & 255], 1);
        col[pos] = (int)(pk >> 8);
    }
}

// ---------------- L1 matmul via MFMA; output pre-scaled: h1' = dis[row]*(x@W1) ----------------

__global__ __launch_bounds__(256) void k_mm1(const float* __restrict__ X,
                                             const unsigned* __restrict__ wsW,
                                             const float* __restrict__ dis,
                                             ushort_t* __restrict__ H,
                                             unsigned* __restrict__ h2zero, int N) {
    const int tid = threadIdx.x;
    if (blockIdx.x == 0 && tid < 16) h2zero[tid] = 0;  // h2 pad row (32 bf16 = 16 dwords)

    const int wv = tid >> 6, lane = tid & 63;
    const int quad = lane >> 4, n16 = lane & 15;
    const int rowbase = blockIdx.x * 64 + wv * 16;
    const int myrow = rowbase + n16;
    const bool rok = (myrow < N);

    float4v acc0 = {}, acc1 = {}, acc2 = {}, acc3 = {};

#pragma unroll
    for (int kc = 0; kc < 4; ++kc) {
        float4 xa = make_float4(0.f, 0.f, 0.f, 0.f), xb = xa;
        if (rok) {
            const float4* p = (const float4*)(X + (long long)myrow * 128 + kc * 32 + quad * 8);
            xa = p[0];
            xb = p[1];
        }
        unsigned pk[4];
        pk[0] = (unsigned)f2bf(xa.x) | ((unsigned)f2bf(xa.y) << 16);
        pk[1] = (unsigned)f2bf(xa.z) | ((unsigned)f2bf(xa.w) << 16);
        pk[2] = (unsigned)f2bf(xb.x) | ((unsigned)f2bf(xb.y) << 16);
        pk[3] = (unsigned)f2bf(xb.z) | ((unsigned)f2bf(xb.w) << 16);
        short8 a;
        a[0] = (short)(pk[0] & 0xffff); a[1] = (short)(pk[0] >> 16);
        a[2] = (short)(pk[1] & 0xffff); a[3] = (short)(pk[1] >> 16);
        a[4] = (short)(pk[2] & 0xffff); a[5] = (short)(pk[2] >> 16);
        a[6] = (short)(pk[3] & 0xffff); a[7] = (short)(pk[3] >> 16);

        const short8* wb = (const short8*)wsW;
        short8 b0 = wb[(kc * 4 + 0) * 64 + lane];
        short8 b1 = wb[(kc * 4 + 1) * 64 + lane];
        short8 b2 = wb[(kc * 4 + 2) * 64 + lane];
        short8 b3 = wb[(kc * 4 + 3) * 64 + lane];

        acc0 = __builtin_amdgcn_mfma_f32_16x16x32_bf16(a, b0, acc0, 0, 0, 0);
        acc1 = __builtin_amdgcn_mfma_f32_16x16x32_bf16(a, b1, acc1, 0, 0, 0);
        acc2 = __builtin_amdgcn_mfma_f32_16x16x32_bf16(a, b2, acc2, 0, 0, 0);
        acc3 = __builtin_amdgcn_mfma_f32_16x16x32_bf16(a, b3, acc3, 0, 0, 0);
    }

#pragma unroll
    for (int i = 0; i < 4; ++i) {
        int row = rowbase + quad * 4 + i;
        if (row < N) {
            float dr = dis[row];
            long long o = (long long)row * 64 + n16;
            H[o]      = f2bf(dr * acc0[i]);
            H[o + 16] = f2bf(dr * acc1[i]);
            H[o + 32] = f2bf(dr * acc2[i]);
            H[o + 48] = f2bf(dr * acc3[i]);
        }
    }
}

// ---------------- fused agg64 + mm2 v3: 8 rows/wave, 8-lane row-groups, no reduce ----------------
// Static strided persistent loop (NO atomic dispenser -- round-2 post-mortem: per-iteration
// same-address device atomics serialized the whole kernel at the fabric).
// lane (t=lane&7, g=lane>>3): row r0+g, h1 channels 8t..8t+7 (one uint4 = 16B slice).
// zbl padded 64->72 f16 per row to kill MFMA-read bank conflicts.

__global__ __launch_bounds__(256, 8) void k_agg64_mm2(const unsigned* __restrict__ h,
                                                      const int* __restrict__ rowptr,
                                                      const int* __restrict__ col,
                                                      const float* __restrict__ dis,
                                                      const float* __restrict__ b1,
                                                      const unsigned* __restrict__ wsW2,
                                                      unsigned* __restrict__ h2, int N) {
    __shared__ __align__(16) _Float16 zbl[4][8][72];  // pad 72: 144B row stride, banks spread
    const int tid = threadIdx.x;
    const int wv = tid >> 6, lane = tid & 63;
    const int t = lane & 7, g = lane >> 3;
    const float4 bqa = ((const float4*)b1)[2 * t];      // channels 8t..8t+3
    const float4 bqb = ((const float4*)b1)[2 * t + 1];  // channels 8t+4..8t+7

    const half8* wfh = (const half8*)wsW2;  // W2 f16 b-frags
    const half8 bf00 = wfh[lane];
    const half8 bf01 = wfh[64 + lane];
    const half8 bf10 = wfh[128 + lane];
    const half8 bf11 = wfh[192 + lane];

    ushort_t* H2u = (ushort_t*)h2;
    const uint4* h4 = (const uint4*)h;
    const int NB = (N + 7) >> 3;
    const int step = gridDim.x * 4;

    for (int rb = blockIdx.x * 4 + wv; rb < NB; rb += step) {
        const int r0 = rb * 8;
        int rp_l = rowptr[min(r0 + min(lane, 8), N)];
        float dis_l = (lane < 8 && r0 + lane < N) ? dis[r0 + lane] : 0.f;
        const int sg = __shfl(rp_l, g);
        const int dg = __shfl(rp_l, g + 1) - sg;
        const float drg = __shfl(dis_l, g);
        float dr03[4];  // dis of rows (lane>>4&1)*4 + i, for the C-store
#pragma unroll
        for (int i = 0; i < 4; ++i) dr03[i] = __shfl(dis_l, ((lane >> 4) & 1) * 4 + i);

        int mc1 = N, mc2 = N, mc3 = N;
        if (t < dg)      mc1 = col[sg + t];
        if (8 + t < dg)  mc2 = col[sg + 8 + t];
        if (16 + t < dg) mc3 = col[sg + 16 + t];

        const int rme = min(r0 + g, N);
        uint4 us = h4[rme * 8 + t];  // self-loop slice
        float2 p0 = make_float2(bf_lo(us.x), bf_hi(us.x));
        float2 p1 = make_float2(bf_lo(us.y), bf_hi(us.y));
        float2 p2 = make_float2(bf_lo(us.z), bf_hi(us.z));
        float2 p3 = make_float2(bf_lo(us.w), bf_hi(us.w));

#define GATX(MC, U)                                                   \
    {                                                                 \
        int s_ = __shfl((MC), (g << 3) + (U));                        \
        uint4 uu = h4[s_ * 8 + t];                                    \
        p0 += make_float2(bf_lo(uu.x), bf_hi(uu.x));                  \
        p1 += make_float2(bf_lo(uu.y), bf_hi(uu.y));                  \
        p2 += make_float2(bf_lo(uu.z), bf_hi(uu.z));                  \
        p3 += make_float2(bf_lo(uu.w), bf_hi(uu.w));                  \
    }
#pragma unroll
        for (int u = 0; u < 8; ++u) GATX(mc1, u)
#pragma unroll
        for (int u = 0; u < 8; ++u) GATX(mc2, u)
#pragma unroll
        for (int u = 0; u < 8; ++u) GATX(mc3, u)
        if (__any(dg > 24)) {
            int mc4 = N;
            if (24 + t < dg) mc4 = col[sg + 24 + t];
#pragma unroll
            for (int u = 0; u < 8; ++u) GATX(mc4, u)
        }
        for (int u = 32; u < dg; ++u) {  // ultra-rare serial tail (same-addr broadcast col)
            int s_ = col[sg + u];
            uint4 uu = h4[s_ * 8 + t];
            p0 += make_float2(bf_lo(uu.x), bf_hi(uu.x));
            p1 += make_float2(bf_lo(uu.y), bf_hi(uu.y));
            p2 += make_float2(bf_lo(uu.z), bf_hi(uu.z));
            p3 += make_float2(bf_lo(uu.w), bf_hi(uu.w));
        }
#undef GATX

        // z = relu(b1 + dr*acc) -> f16, lane writes its own 16B slice; no cross-lane reduce
        {
            float z0 = fmaxf(fmaf(drg, p0.x, bqa.x), 0.f);
            float z1 = fmaxf(fmaf(drg, p0.y, bqa.y), 0.f);
            float z2 = fmaxf(fmaf(drg, p1.x, bqa.z), 0.f);
            float z3 = fmaxf(fmaf(drg, p1.y, bqa.w), 0.f);
            float z4 = fmaxf(fmaf(drg, p2.x, bqb.x), 0.f);
            float z5 = fmaxf(fmaf(drg, p2.y, bqb.y), 0.f);
            float z6 = fmaxf(fmaf(drg, p3.x, bqb.z), 0.f);
            float z7 = fmaxf(fmaf(drg, p3.y, bqb.w), 0.f);
            *(uint4*)&zbl[wv][g][8 * t] =
                make_uint4(pkh(z0, z1), pkh(z2, z3), pkh(z4, z5), pkh(z6, z7));
        }
        __builtin_amdgcn_wave_barrier();

        // batched MFMA: A row = lane&15 (rows 8-15 replicate rows 0-7, C rows 8-15 unused)
        const int zr = lane & 7;
        const int ko = (lane >> 4) * 8;
        half8 af0 = *(const half8*)&zbl[wv][zr][ko];
        half8 af1 = *(const half8*)&zbl[wv][zr][ko + 32];
        float4v c0 = {}, c1 = {};
        c0 = __builtin_amdgcn_mfma_f32_16x16x32_f16(af0, bf00, c0, 0, 0, 0);
        c0 = __builtin_amdgcn_mfma_f32_16x16x32_f16(af1, bf10, c0, 0, 0, 0);
        c1 = __builtin_amdgcn_mfma_f32_16x16x32_f16(af0, bf01, c1, 0, 0, 0);
        c1 = __builtin_amdgcn_mfma_f32_16x16x32_f16(af1, bf11, c1, 0, 0, 0);
        __builtin_amdgcn_wave_barrier();

        // C rows 0-7 live in lanes 0-31 (row = (lane>>4)*4 + reg), col = lane&15
        if (lane < 32) {
            const int li = lane >> 4;
            const int cc = lane & 15;
#pragma unroll
            for (int i = 0; i < 4; ++i) {
                int rr = r0 + li * 4 + i;
                if (rr < N) {
                    H2u[rr * 32 + cc]      = f2bf(dr03[i] * c0[i]);
                    H2u[rr * 32 + 16 + cc] = f2bf(dr03[i] * c1[i]);
                }
            }
        }
    }
}

// ---------------- agg32 v3: 8 rows/wave, 8-lane row-groups, no reduce, static stride ----------------

__global__ __launch_bounds__(256, 8) void k_agg32(const unsigned* __restrict__ h,
                                                  const int* __restrict__ rowptr,
                                                  const int* __restrict__ col,
                                                  const float* __restrict__ dis,
                                                  const float* __restrict__ b,
                                                  float* __restrict__ out, int N) {
    const int tid = threadIdx.x;
    const int wv = tid >> 6, lane = tid & 63;
    const int t = lane & 7, g = lane >> 3;
    const float4 bq = ((const float4*)b)[t];  // channels 4t..4t+3
    const uint2* hw = (const uint2*)h;
    const int NB = (N + 7) >> 3;
    const int step = gridDim.x * 4;

    for (int rb = blockIdx.x * 4 + wv; rb < NB; rb += step) {
        const int r0 = rb * 8;
        int rp_l = rowptr[min(r0 + min(lane, 8), N)];
        float dis_l = (lane < 8 && r0 + lane < N) ? dis[r0 + lane] : 0.f;
        const int sg = __shfl(rp_l, g);
        const int dg = __shfl(rp_l, g + 1) - sg;
        const float drg = __shfl(dis_l, g);

        int mc1 = N, mc2 = N, mc3 = N;
        if (t < dg)      mc1 = col[sg + t];
        if (8 + t < dg)  mc2 = col[sg + 8 + t];
        if (16 + t < dg) mc3 = col[sg + 16 + t];

        const int rme = min(r0 + g, N);
        uint2 us = hw[rme * 8 + t];  // self-loop slice
        float2 p0 = make_float2(bf_lo(us.x), bf_hi(us.x));
        float2 p1 = make_float2(bf_lo(us.y), bf_hi(us.y));

#define GAT2(MC, U)                                                   \
    {                                                                 \
        int s_ = __shfl((MC), (g << 3) + (U));                        \
        uint2 uu = hw[s_ * 8 + t];                                    \
        p0 += make_float2(bf_lo(uu.x), bf_hi(uu.x));                  \
        p1 += make_float2(bf_lo(uu.y), bf_hi(uu.y));                  \
    }
#pragma unroll
        for (int u = 0; u < 8; ++u) GAT2(mc1, u)
#pragma unroll
        for (int u = 0; u < 8; ++u) GAT2(mc2, u)
#pragma unroll
        for (int u = 0; u < 8; ++u) GAT2(mc3, u)
        if (__any(dg > 24)) {
            int mc4 = N;
            if (24 + t < dg) mc4 = col[sg + 24 + t];
#pragma unroll
            for (int u = 0; u < 8; ++u) GAT2(mc4, u)
        }
        for (int u = 32; u < dg; ++u) {
            int s_ = col[sg + u];
            uint2 uu = hw[s_ * 8 + t];
            p0 += make_float2(bf_lo(uu.x), bf_hi(uu.x));
            p1 += make_float2(bf_lo(uu.y), bf_hi(uu.y));
        }
#undef GAT2

        const int rr = r0 + g;
        if (rr < N) {
            float4 o;
            o.x = bq.x + drg * p0.x;
            o.y = bq.y + drg * p0.y;
            o.z = bq.z + drg * p1.x;
            o.w = bq.w + drg * p1.y;
            ((float4*)out)[(long long)rr * 8 + t] = o;
        }
    }
}

extern "C" void kernel_launch(void* const* d_in, const int* in_sizes, int n_in,
                              void* d_out, int out_size, void* d_ws, size_t ws_size,
                              hipStream_t stream) {
    const float* x  = (const float*)d_in[0];
    const int*   ei = (const int*)d_in[1];
    const float* W1 = (const float*)d_in[2];
    const float* b1 = (const float*)d_in[3];
    const float* W2 = (const float*)d_in[4];
    const float* b2 = (const float*)d_in[5];
    float* out = (float*)d_out;

    const int N = in_sizes[0] / IN_CH;
    const int E = in_sizes[1] / 2;
    const int* esrc = ei;
    const int* edst = ei + E;

    int nbk = (N + 255) >> 8;
    if (nbk > MAXB) nbk = MAXB;
    const int per_b = (E + nbk - 1) / nbk;
    const int cap = per_b + per_b / 4 + 256;  // ~20-sigma headroom

    // workspace layout (4-byte units, regions padded to 16); h1/h2 have pad row N
    int* rowptr   = (int*)d_ws;                          // N+1
    int* gcursor  = rowptr + (((N + 1) + 15) & ~15);     // MAXB
    unsigned* wsW = (unsigned*)(gcursor + MAXB);         // 4096 W1-frag + 1024 W2-frag dwords
    int* col      = (int*)(wsW + 5120);                  // E
    float* dis    = (float*)(col + ((E + 15) & ~15));    // N
    ushort_t* h1  = (ushort_t*)(dis + ((N + 15) & ~15)); // (N+1)*64 bf16
    unsigned* scratch = (unsigned*)(h1 + (((long long)(N + 1) * 64 + 31) & ~31LL));
    unsigned* pairs = scratch;        // nbk*cap dwords (~8.4MB), dead after bucket_build
    unsigned* h2    = scratch;        // (N+1)*16 dwords bf16x2, written after pairs dead

    const int B = 256;
    const int PB = (E + EPB - 1) / EPB;
    const int AGG_BLOCKS = 2048;  // 8 blocks/CU, static strided persistent loop

    hipMemsetAsync(gcursor, 0, MAXB * sizeof(int), stream);
    k_partition<<<PB + 5, B, 0, stream>>>(esrc, edst, gcursor, pairs, E, nbk, cap, PB, W1, W2, wsW);
    k_bucket_build<<<nbk, B, 0, stream>>>(pairs, gcursor, rowptr, col, dis,
                                          (unsigned*)(h1 + (long long)N * 64), cap, N);

    k_mm1<<<(N + 63) / 64, B, 0, stream>>>(x, wsW, dis, h1, h2 + (long long)N * 16, N);

    k_agg64_mm2<<<AGG_BLOCKS, B, 0, stream>>>((const unsigned*)h1, rowptr, col, dis, b1,
                                              wsW + 4096, h2, N);

    k_agg32<<<AGG_BLOCKS, B, 0, stream>>>((const unsigned*)h2, rowptr, col, dis, b2, out, N);
}